// Round 7
// baseline (286.582 us; speedup 1.0000x reference)
//
#include <hip/hip_runtime.h>

typedef float f32x4 __attribute__((ext_vector_type(4)));
typedef _Float16 h16x8 __attribute__((ext_vector_type(8)));
typedef _Float16 h16x4 __attribute__((ext_vector_type(4)));

#define GLOAD_LDS16(gp, lp) __builtin_amdgcn_global_load_lds(               \
    (const __attribute__((address_space(1))) void*)(gp),                    \
    (__attribute__((address_space(3))) void*)(lp), 16, 0, 0)

#define BARX do { __builtin_amdgcn_s_barrier(); asm volatile("" ::: "memory"); } while (0)
#define VMW(N) asm volatile("s_waitcnt vmcnt(" #N ")" ::: "memory")

// ---------------------------------------------------------------------------
// cast x (f32) -> f16, 8 elems/thread
__global__ __launch_bounds__(256) void cast_x(const float* __restrict__ x,
                                              _Float16* __restrict__ xh) {
  long i = (long)blockIdx.x * 256 + threadIdx.x;
  f32x4 a = *(const f32x4*)(x + i * 8);
  f32x4 b = *(const f32x4*)(x + i * 8 + 4);
  h16x8 h;
  h[0] = (_Float16)a[0]; h[1] = (_Float16)a[1];
  h[2] = (_Float16)a[2]; h[3] = (_Float16)a[3];
  h[4] = (_Float16)b[0]; h[5] = (_Float16)b[1];
  h[6] = (_Float16)b[2]; h[7] = (_Float16)b[3];
  *(h16x8*)(xh + i * 8) = h;
}

// ---------------------------------------------------------------------------
// transpose + cast weight: in f32 (K x N) row-major -> out f16 (N x K), *scale
__global__ __launch_bounds__(256) void tcw(const float* __restrict__ in,
                                           _Float16* __restrict__ out,
                                           int Kd, int Nd, float scale) {
  __shared__ float tile[64][65];
  const int t = threadIdx.x;
  const int k0 = blockIdx.y * 64, n0 = blockIdx.x * 64;
  const int tr = t >> 4, tc = (t & 15) * 4;
#pragma unroll
  for (int i = 0; i < 4; ++i) {
    int r = i * 16 + tr;
    f32x4 a = *(const f32x4*)(in + (long)(k0 + r) * Nd + n0 + tc);
    tile[r][tc + 0] = a[0]; tile[r][tc + 1] = a[1];
    tile[r][tc + 2] = a[2]; tile[r][tc + 3] = a[3];
  }
  __syncthreads();
#pragma unroll
  for (int i = 0; i < 4; ++i) {
    int r = i * 16 + tr;
    h16x4 h;
#pragma unroll
    for (int q = 0; q < 4; ++q) h[q] = (_Float16)(tile[tc + q][r] * scale);
    *(h16x4*)(out + (long)(n0 + r) * Kd + k0 + tc) = h;
  }
}

// ---------------------------------------------------------------------------
// f16 tile transpose: in (R x C, ld=Cd) -> out (C x R, ld=R), batched
__global__ __launch_bounds__(256) void trans16(const _Float16* __restrict__ in,
                                               _Float16* __restrict__ out,
                                               int R, int Cd, long ibatch, long obatch) {
  __shared__ _Float16 tile[64][72];
  in += (long)blockIdx.z * ibatch;
  out += (long)blockIdx.z * obatch;
  const int t = threadIdx.x;
  const int r0 = blockIdx.y * 64, c0 = blockIdx.x * 64;
  const int tr = t >> 3, tc8 = (t & 7) * 8;
#pragma unroll
  for (int i = 0; i < 2; ++i) {
    int r = i * 32 + tr;
    h16x8 a = *(const h16x8*)(in + (long)(r0 + r) * Cd + c0 + tc8);
    *(h16x8*)(&tile[r][tc8]) = a;
  }
  __syncthreads();
#pragma unroll
  for (int i = 0; i < 2; ++i) {
    int r = i * 32 + tr;
    h16x8 h;
#pragma unroll
    for (int q = 0; q < 8; ++q) h[q] = tile[tc8 + q][r];
    *(h16x8*)(out + (long)(c0 + r) * R + r0 + tc8) = h;
  }
}

// ---------------------------------------------------------------------------
// lambda_full = exp(sum lq1*lk1) - exp(sum lq2*lk2) + 0.8
__global__ __launch_bounds__(1024) void lambda_k(const float* __restrict__ lq1,
                                                 const float* __restrict__ lk1,
                                                 const float* __restrict__ lq2,
                                                 const float* __restrict__ lk2,
                                                 float* __restrict__ lam) {
  __shared__ float sh1[16], sh2[16];
  const int t = threadIdx.x;
  float p1 = lq1[t] * lk1[t];
  float p2 = lq2[t] * lk2[t];
#pragma unroll
  for (int off = 1; off < 64; off <<= 1) {
    p1 += __shfl_xor(p1, off);
    p2 += __shfl_xor(p2, off);
  }
  if ((t & 63) == 0) { sh1[t >> 6] = p1; sh2[t >> 6] = p2; }
  __syncthreads();
  if (t == 0) {
    float s1 = 0.f, s2 = 0.f;
    for (int i = 0; i < 16; ++i) { s1 += sh1[i]; s2 += sh2[i]; }
    lam[0] = __expf(s1) - __expf(s2) + 0.8f;
  }
}

// ---------------------------------------------------------------------------
// C(M x N) = A(M x K) @ B(N x K)^T. Occupancy-first GEMM:
// BM=64*MW, BN=64*NW, BK=32, MW*NW waves, per-wave 64x64 (acc = 64 regs).
// Ring-of-3 LDS (depth-2 prefetch), counted vmcnt (drain slot S, keep S+1;
// 0 only at final step), ONE barrier per K-step. R3-verified swizzle
// (slot sp holds gs=(sp-(r>>1))&3 -> 2-way max, 0 conflicts measured).
// <4,2>: 512 thr, LDS 72KB, launch_bounds(512,4) -> target 2 blocks/CU.
// <2,2>: 256 thr, LDS 48KB -> target 3 blocks/CU. Cross-block TLP hides
// barrier/stage gaps (m97/m114 mechanism). XCD remap; natt axis for S1+S2.
// Requires: M%BM==0, N%BN==0, K%32==0, K>=96.
template <int MW, int NW, typename CT>
__global__ __launch_bounds__(MW * NW * 64, 4) void gemmw(
    const _Float16* __restrict__ A, const _Float16* __restrict__ B,
    CT* __restrict__ C, int K, int lda, int ldb, int ldc,
    long abatch, long bbatch, long cbatch, long a2, long c2, int natt,
    int nbx, int nby) {
  constexpr int BM = MW * 64, BN = NW * 64;
  constexpr int THREADS = MW * NW * 64;
  constexpr int nA = BM * 4 / THREADS;   // A 16B-chunks per thread per K-step
  constexpr int nB = BN * 4 / THREADS;
  constexpr int L = nA + nB;             // loads in one stage() call
  __shared__ _Float16 As[3][BM][32];
  __shared__ _Float16 Bs[3][BN][32];

  // bijective XCD-aware remap (m204); grids are multiples of 8
  const int nwg = gridDim.x;
  const int orig = blockIdx.x;
  const int qd = nwg >> 3, rm = nwg & 7;
  const int xcd = orig & 7, sub = orig >> 3;
  const int wgid = (xcd < rm ? xcd * (qd + 1) : rm * (qd + 1) + (xcd - rm) * qd) + sub;

  const int z = wgid / (nbx * nby);
  const int rem = wgid - z * nbx * nby;
  const int by = rem / nbx;
  const int bx = rem - by * nbx;
  const int att = z % natt;
  const int bz = z / natt;

  const int t = threadIdx.x;
  const int lane = t & 63, wv = t >> 6;
  const int wm = wv >> 1, wn = wv & 1;   // NW == 2 always here
  const int lg = lane >> 4, l15 = lane & 15;

  const _Float16* Ab = A + (long)bz * abatch + (long)att * a2 + (long)(by * BM) * lda;
  const _Float16* Bb = B + (long)bz * bbatch + (long)att * a2 + (long)(bx * BN) * ldb;

  // stage K-step S into ring slot `slot`; swizzled global source (R3 layout)
  auto stage = [&](int slot, int S) {
    const long ko = (long)S * 32;
#pragma unroll
    for (int j = 0; j < nA; ++j) {
      const int e = t + j * THREADS;
      const int r = e >> 2;
      const int gs = ((e & 3) - (r >> 1)) & 3;
      GLOAD_LDS16(Ab + (long)r * lda + ko + gs * 8, &As[slot][0][0] + e * 8);
    }
#pragma unroll
    for (int j = 0; j < nB; ++j) {
      const int e = t + j * THREADS;
      const int r = e >> 2;
      const int gs = ((e & 3) - (r >> 1)) & 3;
      GLOAD_LDS16(Bb + (long)r * ldb + ko + gs * 8, &Bs[slot][0][0] + e * 8);
    }
  };

  // reader offsets (f16 units within a ring slot)
  int offA[4], offB[4];
#pragma unroll
  for (int m = 0; m < 4; ++m) {
    const int r = wm * 64 + m * 16 + l15;
    offA[m] = (r * 4 + ((lg + (r >> 1)) & 3)) * 8;
  }
#pragma unroll
  for (int n = 0; n < 4; ++n) {
    const int r = wn * 64 + n * 16 + l15;
    offB[n] = (r * 4 + ((lg + (r >> 1)) & 3)) * 8;
  }

  f32x4 acc[4][4] = {};
  const int NS = K >> 5;

  stage(0, 0); stage(1, 1);
  int cur = 0, nx2 = 2;

  for (int S = 0; S < NS; ++S) {
    // drain slot S's loads; keep slot S+1's in flight (counted, never 0 mid-loop)
    if (S == NS - 1) VMW(0);
    else { if constexpr (L == 3) VMW(3); else VMW(4); }
    BARX;  // slot-S data visible to all; ring slot (S+2)%3 == (S-1)%3 is free

    if (S + 2 < NS) stage(nx2, S + 2);

    const _Float16* Ap = &As[cur][0][0];
    const _Float16* Bp = &Bs[cur][0][0];
    h16x8 a[4], b[4];
#pragma unroll
    for (int m = 0; m < 4; ++m) a[m] = *(const h16x8*)(Ap + offA[m]);
#pragma unroll
    for (int n = 0; n < 4; ++n) b[n] = *(const h16x8*)(Bp + offB[n]);
    __builtin_amdgcn_s_setprio(1);
#pragma unroll
    for (int m = 0; m < 4; ++m)
#pragma unroll
      for (int n = 0; n < 4; ++n)
        acc[m][n] = __builtin_amdgcn_mfma_f32_16x16x32_f16(a[m], b[n], acc[m][n], 0, 0, 0);
    __builtin_amdgcn_s_setprio(0);

    cur = (cur == 2) ? 0 : cur + 1;
    nx2 = (nx2 == 2) ? 0 : nx2 + 1;
  }

  CT* Cb = C + (long)bz * cbatch + (long)att * c2;
  const int crow0 = by * BM + wm * 64;
  const int ccol0 = bx * BN + wn * 64;
#pragma unroll
  for (int m = 0; m < 4; ++m)
#pragma unroll
    for (int n = 0; n < 4; ++n)
#pragma unroll
      for (int j = 0; j < 4; ++j)
        Cb[(long)(crow0 + m * 16 + lg * 4 + j) * ldc + ccol0 + n * 16 + l15] =
            (CT)acc[m][n][j];
}

// ---------------------------------------------------------------------------
// one wave per row: diff = softmax(S1) - lam * softmax(S2), f16 in/out
__global__ __launch_bounds__(256) void softmax_diff(const _Float16* __restrict__ S1,
                                                    const _Float16* __restrict__ S2,
                                                    _Float16* __restrict__ D,
                                                    const float* __restrict__ lamp) {
  const long row = (long)blockIdx.x * 4 + (threadIdx.x >> 6);
  const int lane = threadIdx.x & 63;
  const float lam = *lamp;
  const _Float16* s1 = S1 + row * 2048;
  const _Float16* s2 = S2 + row * 2048;
  float v1[32], v2[32];
  float m1 = -3e38f, m2 = -3e38f;
#pragma unroll
  for (int j = 0; j < 4; ++j) {
    h16x8 a = ((const h16x8*)s1)[j * 64 + lane];
    h16x8 b = ((const h16x8*)s2)[j * 64 + lane];
#pragma unroll
    for (int q = 0; q < 8; ++q) {
      v1[j * 8 + q] = (float)a[q]; v2[j * 8 + q] = (float)b[q];
      m1 = fmaxf(m1, v1[j * 8 + q]); m2 = fmaxf(m2, v2[j * 8 + q]);
    }
  }
#pragma unroll
  for (int off = 1; off < 64; off <<= 1) {
    m1 = fmaxf(m1, __shfl_xor(m1, off));
    m2 = fmaxf(m2, __shfl_xor(m2, off));
  }
  float l1 = 0.f, l2 = 0.f;
#pragma unroll
  for (int e = 0; e < 32; ++e) {
    v1[e] = __expf(v1[e] - m1); l1 += v1[e];
    v2[e] = __expf(v2[e] - m2); l2 += v2[e];
  }
#pragma unroll
  for (int off = 1; off < 64; off <<= 1) {
    l1 += __shfl_xor(l1, off);
    l2 += __shfl_xor(l2, off);
  }
  const float r1 = 1.f / l1, r2 = lam / l2;
  _Float16* d = D + row * 2048;
#pragma unroll
  for (int j = 0; j < 4; ++j) {
    h16x8 h;
#pragma unroll
    for (int q = 0; q < 8; ++q)
      h[q] = (_Float16)(v1[j * 8 + q] * r1 - v2[j * 8 + q] * r2);
    ((h16x8*)d)[j * 64 + lane] = h;
  }
}

// ---------------------------------------------------------------------------
// one wave per row: out = O / sqrt(mean(O^2) + eps) * 0.2, f16 in, f32 out
__global__ __launch_bounds__(256) void rmsnorm(const _Float16* __restrict__ O,
                                               float* __restrict__ out) {
  const long row = (long)blockIdx.x * 4 + (threadIdx.x >> 6);
  const int lane = threadIdx.x & 63;
  const _Float16* o = O + row * 1024;
  h16x8 a = ((const h16x8*)o)[lane];
  h16x8 b = ((const h16x8*)o)[64 + lane];
  float xa[8], xb[8];
  float ss = 0.f;
#pragma unroll
  for (int q = 0; q < 8; ++q) {
    xa[q] = (float)a[q]; xb[q] = (float)b[q];
    ss += xa[q] * xa[q] + xb[q] * xb[q];
  }
#pragma unroll
  for (int off = 1; off < 64; off <<= 1) ss += __shfl_xor(ss, off);
  const float s = 0.2f * rsqrtf(ss * (1.f / 1024.f) + 1e-5f);
  float* po = out + row * 1024;
  f32x4 r;
#pragma unroll
  for (int q = 0; q < 4; ++q) r[q] = xa[q] * s;
  *(f32x4*)(po + lane * 8) = r;
#pragma unroll
  for (int q = 0; q < 4; ++q) r[q] = xa[4 + q] * s;
  *(f32x4*)(po + lane * 8 + 4) = r;
#pragma unroll
  for (int q = 0; q < 4; ++q) r[q] = xb[q] * s;
  *(f32x4*)(po + 512 + lane * 8) = r;
#pragma unroll
  for (int q = 0; q < 4; ++q) r[q] = xb[4 + q] * s;
  *(f32x4*)(po + 512 + lane * 8 + 4) = r;
}

// ---------------------------------------------------------------------------
extern "C" void kernel_launch(void* const* d_in, const int* in_sizes, int n_in,
                              void* d_out, int out_size, void* d_ws, size_t ws_size,
                              hipStream_t stream) {
  const float* x   = (const float*)d_in[0];
  const float* wq  = (const float*)d_in[1];
  const float* wk  = (const float*)d_in[2];
  const float* wv  = (const float*)d_in[3];
  const float* lq1 = (const float*)d_in[4];
  const float* lk1 = (const float*)d_in[5];
  const float* lq2 = (const float*)d_in[6];
  const float* lk2 = (const float*)d_in[7];
  float* out = (float*)d_out;

  const size_t MB = 1ull << 20;
  char* ws = (char*)d_ws;
  _Float16* xh   = (_Float16*)(ws + 0);          // 16MB  8192x1024
  _Float16* Wp   = (_Float16*)(ws + 16 * MB);    // 10MB  5120x1024 [q|k|v], B^T
  _Float16* qkv  = (_Float16*)(ws + 26 * MB);    // 80MB  8192x5120
  _Float16* vt   = (_Float16*)(ws + 106 * MB);   // 16MB  4 x 1024x2048
  _Float16* S1   = (_Float16*)(ws + 122 * MB);   // 32MB  4 x 2048x2048
  _Float16* S2   = (_Float16*)(ws + 154 * MB);   // 32MB
  float*    lam  = (float*)(ws + 186 * MB);      // 4B
  _Float16* diff = (_Float16*)(ws + 26 * MB);    // 32MB, reuses dead qkv
  _Float16* opre = (_Float16*)(ws + 58 * MB);    // 16MB, reuses dead qkv

  const float scale = 0.17677669529663689f;  // 1024^-0.25

  cast_x<<<4096, 256, 0, stream>>>(x, xh);
  tcw<<<dim3(32, 16), 256, 0, stream>>>(wq, Wp, 1024, 2048, scale);
  tcw<<<dim3(32, 16), 256, 0, stream>>>(wk, Wp + 2048l * 1024, 1024, 2048, 1.0f);
  tcw<<<dim3(16, 16), 256, 0, stream>>>(wv, Wp + 4096l * 1024, 1024, 1024, 1.0f);
  lambda_k<<<1, 1024, 0, stream>>>(lq1, lk1, lq2, lk2, lam);

  // fused projection: qkv = xh @ Wp^T  (8192 x 5120, K=1024); 256x128 tiles
  gemmw<4, 2, _Float16><<<1280, 512, 0, stream>>>(xh, Wp, qkv, 1024, 1024, 1024, 5120,
                                                  0, 0, 0, 0, 0, 1, 40, 32);

  // v region (cols 4096..5119) -> vt (b,1024,2048)
  trans16<<<dim3(16, 32, 4), 256, 0, stream>>>(qkv + 4096, vt, 2048, 5120,
                                               2048l * 5120, 1024l * 2048);

  // S1 and S2 fused (natt=2): S_p = q_p @ k_p^T, f16 out; 256x128 tiles
  gemmw<4, 2, _Float16><<<1024, 512, 0, stream>>>(qkv, qkv + 2048, S1, 1024, 5120, 5120, 2048,
                                                  2048l * 5120, 2048l * 5120, 2048l * 2048,
                                                  1024, 16777216l, 2, 16, 8);

  softmax_diff<<<2048, 256, 0, stream>>>(S1, S2, diff, lam);

  // opre = diff @ vt^T  (K = 2048); 128x128 tiles, 3 blocks/CU
  gemmw<2, 2, _Float16><<<512, 256, 0, stream>>>(diff, vt, opre, 2048, 2048, 2048, 1024,
                                                 2048l * 2048, 1024l * 2048, 2048l * 1024,
                                                 0, 0, 1, 8, 16);

  rmsnorm<<<2048, 256, 0, stream>>>(opre, out);
}